// Round 9
// baseline (69.249 us; speedup 1.0000x reference)
//
#include <hip/hip_runtime.h>
#include <hip/hip_bf16.h>

#define NUM_GT 25
#define NUM_PRED 40
#define TILE 8192            // voxels per block-tile
#define TILE_W (TILE / 4)    // 2048 packed u32 words
#define GRID 2048
#define BLOCK 256

// ws layout (u32 words):
//   [r*65 + s], r=0..63, s=0..64 : partial SAD sums; sbin s: 0..24 = g_gt(s),
//                                  25..64 = g_pr(s-25)
//   [4160 + p], p=0..40          : overlap bitmask row p
#define WS_OV    4160
#define WS_WORDS (4160 + 41)

// ---------------------------------------------------------------------------
// Phase-2 helper: wave scans the whole packed tile in LDS for NB bins.
// acc count <= 17 per wave => comfortably arch-VGPR (no AGPR split / no
// v_accvgpr round-trips, the hidden 3x tax of rounds 4-8).
// ---------------------------------------------------------------------------
template <int NB>
__device__ __forceinline__ void sad_scan_flush(
    const unsigned* __restrict__ src, int kbase, int sbin0,
    unsigned* shist, int lane)
{
    unsigned acc[NB];
    #pragma unroll
    for (int b = 0; b < NB; ++b) acc[b] = 0u;

    #pragma unroll
    for (int j = 0; j < TILE_W / (64 * 4); ++j) {        // 8 x ds_read_b128
        const uint4 w = *(const uint4*)&src[(lane + j * 64) * 4];
        #pragma unroll
        for (int b = 0; b < NB; ++b) {
            const unsigned K = (unsigned)((kbase + b) * 0x01010101u);
            asm("v_sad_u8 %0, %1, %2, %0" : "+v"(acc[b]) : "v"(w.x), "s"(K));
            asm("v_sad_u8 %0, %1, %2, %0" : "+v"(acc[b]) : "v"(w.y), "s"(K));
            asm("v_sad_u8 %0, %1, %2, %0" : "+v"(acc[b]) : "v"(w.z), "s"(K));
            asm("v_sad_u8 %0, %1, %2, %0" : "+v"(acc[b]) : "v"(w.w), "s"(K));
        }
    }
    #pragma unroll
    for (int b = 0; b < NB; ++b) {
        unsigned c = acc[b];
        c += __shfl_down(c, 32, 64);
        c += __shfl_down(c, 16, 64);
        c += __shfl_down(c, 8, 64);
        c += __shfl_down(c, 4, 64);
        c += __shfl_down(c, 2, 64);
        c += __shfl_down(c, 1, 64);
        if (lane == 0) atomicAdd(&shist[sbin0 + b], c);
    }
}

// ---------------------------------------------------------------------------
// Tile kernel: phase 1 = coalesced stream -> byte-pack -> LDS (+ overlap
// test-then-set from registers); phase 2 = wave-owned-bin SAD over the tile.
// ---------------------------------------------------------------------------
__global__ __launch_bounds__(BLOCK) void hist_kernel(
    const float* __restrict__ pred, const int* __restrict__ gt,
    unsigned* __restrict__ ws, int n)
{
    __shared__ __align__(16) unsigned lds_gt[TILE_W];   // 8 KB
    __shared__ __align__(16) unsigned lds_pr[TILE_W];   // 8 KB
    __shared__ unsigned sovl[64];
    __shared__ unsigned shist[65];

    const int tid  = threadIdx.x;
    const int lane = tid & 63;
    const int wave = tid >> 6;

    if (tid < 64) sovl[tid] = 0u;
    if (tid < 65) shist[tid] = 0u;
    __syncthreads();

    const int ntiles = n / TILE;
    const float4* __restrict__ p4 = (const float4*)pred;
    const int4* __restrict__  g4 = (const int4*)gt;

    for (int tile = blockIdx.x; tile < ntiles; tile += GRID) {
        const int wbase = tile * TILE_W;

        // ---- phase 1: stream + pack + stage (8 unrolled iters, 16 loads) ----
        #pragma unroll
        for (int it = 0; it < TILE_W / BLOCK; ++it) {
            const int w = it * BLOCK + tid;
            int4  g = g4[wbase + w];
            float4 p = p4[wbase + w];
            unsigned a0=(unsigned)g.x, a1=(unsigned)g.y;
            unsigned a2=(unsigned)g.z, a3=(unsigned)g.w;
            unsigned b0=(unsigned)p.x, b1=(unsigned)p.y;
            unsigned b2=(unsigned)p.z, b3=(unsigned)p.w;

            unsigned ok = (sovl[b0 & 63] >> (a0 & 31))
                        & (sovl[b1 & 63] >> (a1 & 31))
                        & (sovl[b2 & 63] >> (a2 & 31))
                        & (sovl[b3 & 63] >> (a3 & 31));
            if (!(ok & 1u)) {                     // rare after warm-up
                atomicOr(&sovl[b0 & 63], 1u << (a0 & 31));
                atomicOr(&sovl[b1 & 63], 1u << (a1 & 31));
                atomicOr(&sovl[b2 & 63], 1u << (a2 & 31));
                atomicOr(&sovl[b3 & 63], 1u << (a3 & 31));
            }
            lds_gt[w] = a0 | (a1 << 8) | (a2 << 16) | (a3 << 24);
            lds_pr[w] = b0 | (b1 << 8) | (b2 << 16) | (b3 << 24);
        }
        __syncthreads();

        // ---- phase 2: wave-owned bins (17/8+8/16/16 = 65 sbins) ----
        if (wave == 0) {
            sad_scan_flush<17>(lds_gt, 0, 0, shist, lane);
        } else if (wave == 1) {
            sad_scan_flush<8>(lds_gt, 17, 17, shist, lane);
            sad_scan_flush<8>(lds_pr, 0, 25, shist, lane);
        } else if (wave == 2) {
            sad_scan_flush<16>(lds_pr, 8, 33, shist, lane);
        } else {
            sad_scan_flush<16>(lds_pr, 24, 49, shist, lane);
        }
        __syncthreads();     // tile LDS reusable
    }

    // remainder voxels (n % TILE; none for 256^3) — defensive
    if (blockIdx.x == 0 && tid == 0) {
        for (int v = ntiles * TILE; v < n; ++v) {
            int p = (int)pred[v];
            int g = gt[v];
            for (int b = 0; b < 25; ++b) atomicAdd(&ws[b], (unsigned)abs(g - b));
            for (int b = 0; b < 40; ++b) atomicAdd(&ws[25 + b], (unsigned)abs(p - b));
            atomicOr(&ws[WS_OV + min(max(p, 0), NUM_PRED)], 1u << (g & 31));
        }
    }

    __syncthreads();
    // ---- flush: one 65-word partial row per block (32 adds/address) ----
    const int row = blockIdx.x & 63;
    if (tid < 65) {
        unsigned s = shist[tid];
        if (s) atomicAdd(&ws[row * 65 + tid], s);
    }
    if (tid < 41) {
        unsigned v = sovl[tid];
        if (v) atomicOr(&ws[WS_OV + tid], v);
    }
}

// ---------------------------------------------------------------------------
// Finisher: sum 64 partial rows, then exact second-difference counts (int64)
// + fp64 dice (proven absmax = 0).
// ---------------------------------------------------------------------------
__global__ __launch_bounds__(128) void finish_kernel(
    const unsigned* __restrict__ ws, float* __restrict__ out, int n)
{
    __shared__ long long gsum[65];
    __shared__ long long psz[41];
    __shared__ unsigned ovs[41];
    const int t = threadIdx.x;

    if (t < 65) {
        unsigned s = 0;
        for (int r = 0; r < 64; ++r) s += ws[r * 65 + t];
        gsum[t] = (long long)s;
    }
    if (t < 41) ovs[t] = ws[WS_OV + t];
    __syncthreads();

    const long long N = n;
    if (t < 41) {                            // pred_sizes[P], P = t
        const long long Sp = gsum[25];
        int P = t;
        long long f;
        if (P == 0)       f = (N - gsum[25 + 0] + gsum[25 + 1]) / 2;
        else if (P <= 38) f = (gsum[25 + P - 1] - 2 * gsum[25 + P] + gsum[25 + P + 1]) / 2;
        else if (P == 39) f = (gsum[25 + 38] - 2 * gsum[25 + 39] + (40 * N - Sp)) / 2;
        else              f = (gsum[25 + 39] - 39 * N + Sp) / 2;   // P = 40
        psz[P] = f;
    }
    __syncthreads();

    if (t < 64) {
        const int lane = t;
        const long long Sg = gsum[0];
        double dice = 0.0;
        int present = 0;
        if (lane < 25) {                     // gt component label L = lane+1
            int L = lane + 1;
            long long gs;
            if (L <= 23)      gs = (gsum[L - 1] - 2 * gsum[L] + gsum[L + 1]) / 2;
            else if (L == 24) gs = (gsum[23] - 2 * gsum[24] + (25 * N - Sg)) / 2;
            else              gs = (gsum[24] - 24 * N + Sg) / 2;   // L = 25
            if (gs > 0) {
                present = 1;
                double un = 0.0;
                const unsigned bit = 1u << L;
                for (int p = 0; p < 41; ++p)
                    if (ovs[p] & bit) un += (double)psz[p];
                dice = 2.0 * (double)gs / (un + (double)gs + 1.0);
            }
        }
        int fp = 0;
        if (lane < 41) {
            if (psz[lane] > 0 && (ovs[lane] & 0x3FFFFFEu) == 0) fp = 1;
        }

        int num_gt = __popcll(__ballot(present != 0));
        int nfp    = __popcll(__ballot(fp != 0));
        #pragma unroll
        for (int o = 32; o >= 1; o >>= 1) dice += __shfl_xor(dice, o, 64);

        if (lane == 0) out[0] = (float)(dice / (double)(num_gt + nfp));
    }
}

extern "C" void kernel_launch(void* const* d_in, const int* in_sizes, int n_in,
                              void* d_out, int out_size, void* d_ws, size_t ws_size,
                              hipStream_t stream) {
    const float* pred = (const float*)d_in[0];
    const int* gt = (const int*)d_in[1];
    float* out = (float*)d_out;
    unsigned* ws = (unsigned*)d_ws;
    const int n = in_sizes[0];

    hipMemsetAsync(ws, 0, WS_WORDS * sizeof(unsigned), stream);

    hist_kernel<<<GRID, BLOCK, 0, stream>>>(pred, gt, ws, n);
    finish_kernel<<<1, 128, 0, stream>>>(ws, out, n);
}